// Round 4
// baseline (506.452 us; speedup 1.0000x reference)
//
#include <hip/hip_runtime.h>

#define T_STEPS 128
#define B_SIZE  32768
#define F_DIM   8
#define H_DIM   64

#define BLOCK_THREADS 128                 // 2 waves = one 32-sample team (2 groups of 16)
#define GRID_BLOCKS   (B_SIZE / 32)       // 1024

typedef float f32x4 __attribute__((ext_vector_type(4)));
typedef short bfrag __attribute__((ext_vector_type(8)));   // 8 bf16 (4 VGPRs)
typedef unsigned int u32x4 __attribute__((ext_vector_type(4)));

#define MFMA16(A, B, C) __builtin_amdgcn_mfma_f32_16x16x32_bf16((A), (B), (C), 0, 0, 0)

__device__ __forceinline__ short f2bf(float f) { return __builtin_bit_cast(short, (__bf16)f); }
__device__ __forceinline__ float4 ld4(const void* p) { return *(const float4*)p; }

constexpr float S1 = 1.4426950408889634f;  // log2(e)   -> folded into r,z weights
constexpr float S2 = 2.f * S1;             // 2*log2(e) -> folded into n weights

// Layout (verified rounds 2-3):
//  A/B frag elem e -> k = 32*kt + 16*(e>>2) + 4*g + (e&3); A row / B col = lane&15
//  C/D: col = lane&15 (sample), row = 4*g + reg (tile tt covers rows 16*tt..16*tt+15)
// Team split: wave w owns h-units [32w, 32w+32) == B k-tile kt=w; exchange via LDS.
// Each wave runs TWO independent 16-sample groups through shared weight registers.

__global__ __launch_bounds__(BLOCK_THREADS, 2)
void seq2seq_ilp2_kernel(const float* __restrict__ inputs, const float* __restrict__ target,
                         const float* __restrict__ eWih, const float* __restrict__ eWhh,
                         const float* __restrict__ ebih, const float* __restrict__ ebhh,
                         const float* __restrict__ dWih, const float* __restrict__ dWhh,
                         const float* __restrict__ dbih, const float* __restrict__ dbhh,
                         const float* __restrict__ oW, const float* __restrict__ ob,
                         float* __restrict__ out)
{
    __shared__ u32x4 sEx[2][2][2][64];   // [parity][wave][group][lane] = 8 KB

    const int tid  = threadIdx.x;
    const int lane = tid & 63;
    const int w    = tid >> 6;        // wave id in team (0/1)
    const int c    = lane & 15;       // sample col
    const int g    = lane >> 4;       // lane group

    bfrag wr[2][2], wz[2][2], whn[2][2];   // [tl][j]: j=0 -> own kt(=w), j=1 -> partner
    bfrag xr[2], xz[2], xnw[2];            // x-ktile A-frags (k<8 = Wih, k==8 = bias row)
    f32x4 bhn[2];                          // bhh n-rows (scaled) -> acc-init for aHN

    auto load_phase = [&](const float* __restrict__ Wih, const float* __restrict__ Whh,
                          const float* __restrict__ bih, const float* __restrict__ bhh) {
#pragma unroll
        for (int tl = 0; tl < 2; ++tl) {
            const int tt = 2 * w + tl;
            const int rowR = 16 * tt + c, rowZ = rowR + 64, rowN = rowR + 128;
#pragma unroll
            for (int j = 0; j < 2; ++j) {
                const int kt = (j == 0) ? w : 1 - w;
                bfrag fr, fz, fn;
#pragma unroll
                for (int e = 0; e < 8; ++e) {
                    const int k = 32 * kt + 16 * (e >> 2) + 4 * g + (e & 3);
                    fr[e] = f2bf(Whh[rowR * H_DIM + k] * S1);
                    fz[e] = f2bf(Whh[rowZ * H_DIM + k] * S1);
                    fn[e] = f2bf(Whh[rowN * H_DIM + k] * S2);
                }
                wr[tl][j] = fr; wz[tl][j] = fz; whn[tl][j] = fn;
            }
            bfrag axr, axz, axn;
#pragma unroll
            for (int e = 0; e < 8; ++e) {
                const int k = 16 * (e >> 2) + 4 * g + (e & 3);
                float vr = 0.f, vz = 0.f, vn = 0.f;
                if (k < F_DIM) {
                    vr = Wih[rowR * F_DIM + k]; vz = Wih[rowZ * F_DIM + k]; vn = Wih[rowN * F_DIM + k];
                } else if (k == F_DIM) {
                    vr = bih[rowR] + bhh[rowR]; vz = bih[rowZ] + bhh[rowZ]; vn = bih[rowN];
                }
                axr[e] = f2bf(vr * S1); axz[e] = f2bf(vz * S1); axn[e] = f2bf(vn * S2);
            }
            xr[tl] = axr; xz[tl] = axz; xnw[tl] = axn;
#pragma unroll
            for (int r4 = 0; r4 < 4; ++r4) bhn[tl][r4] = bhh[128 + 16 * tt + 4 * g + r4] * S2;
        }
    };

    f32x4 hc[2][2] = {{{0.f,0.f,0.f,0.f},{0.f,0.f,0.f,0.f}},
                      {{0.f,0.f,0.f,0.f},{0.f,0.f,0.f,0.f}}};   // [grp][tl]
    bfrag hl[2] = {(bfrag){0,0,0,0,0,0,0,0}, (bfrag){0,0,0,0,0,0,0,0}};
    bfrag ho[2] = {(bfrag){0,0,0,0,0,0,0,0}, (bfrag){0,0,0,0,0,0,0,0}};
    bfrag bx0 = (bfrag){0,0,0,0,0,0,0,0};     // ones row at k==8 -> g==2, e==0
    if (g == 2) bx0[0] = f2bf(1.f);

    auto step = [&](bfrag& HL, const bfrag HO, const bfrag bx, f32x4 (&HC)[2]) {
#pragma unroll
        for (int tl = 0; tl < 2; ++tl) {
            f32x4 aR = {0.f,0.f,0.f,0.f}, aZ = {0.f,0.f,0.f,0.f};
            f32x4 aIN = {0.f,0.f,0.f,0.f};
            f32x4 aHN = bhn[tl];
            aR = MFMA16(wr[tl][0], HL, aR);   aR = MFMA16(wr[tl][1], HO, aR);   aR = MFMA16(xr[tl], bx, aR);
            aZ = MFMA16(wz[tl][0], HL, aZ);   aZ = MFMA16(wz[tl][1], HO, aZ);   aZ = MFMA16(xz[tl], bx, aZ);
            aHN = MFMA16(whn[tl][0], HL, aHN); aHN = MFMA16(whn[tl][1], HO, aHN);
            aIN = MFMA16(xnw[tl], bx, aIN);
#pragma unroll
            for (int r4 = 0; r4 < 4; ++r4) {
                const float rg = __builtin_amdgcn_rcpf(1.f + __builtin_amdgcn_exp2f(-aR[r4]));
                const float zg = __builtin_amdgcn_rcpf(1.f + __builtin_amdgcn_exp2f(-aZ[r4]));
                const float np = aIN[r4] + rg * aHN[r4];
                const float ng = 1.f - 2.f * __builtin_amdgcn_rcpf(__builtin_amdgcn_exp2f(np) + 1.f);
                HC[tl][r4] = ng + zg * (HC[tl][r4] - ng);
            }
        }
        bfrag nl;
#pragma unroll
        for (int e = 0; e < 8; ++e) nl[e] = f2bf(HC[e >> 2][e & 3]);
        HL = nl;
    };

    auto make_bx = [&](const float4 xv) {
        bfrag bx = bx0;
        if (g < 2) { bx[0] = f2bf(xv.x); bx[1] = f2bf(xv.y); bx[2] = f2bf(xv.z); bx[3] = f2bf(xv.w); }
        return bx;
    };

    // byte offset of (sample-group grp, this lane's 4 floats) within one time-slab
    const unsigned istep = B_SIZE * F_DIM * 4;
    const unsigned off0  = ((unsigned)(blockIdx.x * 32 + c) * F_DIM + 4 * g) * 4;  // grp adds +512

    // ================= encoder =================
    load_phase(eWih, eWhh, ebih, ebhh);
    int p = 0;
    float4 xn[2] = {make_float4(0.f,0.f,0.f,0.f), make_float4(0.f,0.f,0.f,0.f)};
    if (g < 2) { xn[0] = ld4((const char*)inputs + off0); xn[1] = ld4((const char*)inputs + off0 + 512); }
    unsigned ioff = off0 + istep;   // offset of step t+1's x
#pragma unroll 1
    for (int t = 0; t < T_STEPS; ++t) {
#pragma unroll
        for (int grp = 0; grp < 2; ++grp) {
            const float4 xv = xn[grp];
            if (g < 2 && t + 1 < T_STEPS) xn[grp] = ld4((const char*)inputs + ioff + 512 * grp);
            step(hl[grp], ho[grp], make_bx(xv), hc[grp]);
        }
        ioff += istep;
        sEx[p][w][0][lane] = __builtin_bit_cast(u32x4, hl[0]);
        sEx[p][w][1][lane] = __builtin_bit_cast(u32x4, hl[1]);
        __syncthreads();
        ho[0] = __builtin_bit_cast(bfrag, sEx[p][w ^ 1][0][lane]);
        ho[1] = __builtin_bit_cast(bfrag, sEx[p][w ^ 1][1][lane]);
        p ^= 1;
    }

    // ================= decoder =================
    load_phase(dWih, dWhh, dbih, dbhh);
    bfrag wo[2];   // out-proj A-frags (wave 0 uses): j <-> kt j
    f32x4 obv;
#pragma unroll
    for (int j = 0; j < 2; ++j)
#pragma unroll
        for (int e = 0; e < 8; ++e) {
            const int k = 32 * j + 16 * (e >> 2) + 4 * g + (e & 3);
            wo[j][e] = f2bf((c < F_DIM) ? oW[c * H_DIM + k] : 0.f);
        }
#pragma unroll
    for (int r4 = 0; r4 < 4; ++r4) obv[r4] = (g < 2) ? ob[4 * g + r4] : 0.f;

    unsigned toff = off0;           // target[t] feeds x_{t+1}
    unsigned ooff = off0;
    xn[0] = xn[1] = make_float4(0.f, 0.f, 0.f, 0.f);   // x_0 = 0
#pragma unroll 1
    for (int t = 0; t < T_STEPS; ++t) {
#pragma unroll
        for (int grp = 0; grp < 2; ++grp) {
            const float4 xv = xn[grp];
            if (g < 2 && t + 1 < T_STEPS) xn[grp] = ld4((const char*)target + toff + 512 * grp);
            step(hl[grp], ho[grp], make_bx(xv), hc[grp]);
        }
        toff += istep;
        sEx[p][w][0][lane] = __builtin_bit_cast(u32x4, hl[0]);
        sEx[p][w][1][lane] = __builtin_bit_cast(u32x4, hl[1]);
        __syncthreads();
        ho[0] = __builtin_bit_cast(bfrag, sEx[p][w ^ 1][0][lane]);
        ho[1] = __builtin_bit_cast(bfrag, sEx[p][w ^ 1][1][lane]);
        p ^= 1;
        if (w == 0) {   // y = h_new @ oW^T + ob ; C row = f(=4g+r4, g<2), col = sample
#pragma unroll
            for (int grp = 0; grp < 2; ++grp) {
                f32x4 aO = obv;
                aO = MFMA16(wo[0], hl[grp], aO);
                aO = MFMA16(wo[1], ho[grp], aO);
                if (g < 2) {
                    float4 o; o.x = aO[0]; o.y = aO[1]; o.z = aO[2]; o.w = aO[3];
                    *(float4*)((char*)out + ooff + 512 * grp) = o;
                }
            }
        }
        ooff += istep;
    }
}

extern "C" void kernel_launch(void* const* d_in, const int* in_sizes, int n_in,
                              void* d_out, int out_size, void* d_ws, size_t ws_size,
                              hipStream_t stream) {
    (void)in_sizes; (void)n_in; (void)d_ws; (void)ws_size; (void)out_size;
    const float* inputs = (const float*)d_in[0];
    const float* target = (const float*)d_in[1];
    const float* eWih   = (const float*)d_in[2];
    const float* eWhh   = (const float*)d_in[3];
    const float* ebih   = (const float*)d_in[4];
    const float* ebhh   = (const float*)d_in[5];
    const float* dWih   = (const float*)d_in[6];
    const float* dWhh   = (const float*)d_in[7];
    const float* dbih   = (const float*)d_in[8];
    const float* dbhh   = (const float*)d_in[9];
    const float* oW     = (const float*)d_in[10];
    const float* ob     = (const float*)d_in[11];
    float* out = (float*)d_out;

    seq2seq_ilp2_kernel<<<dim3(GRID_BLOCKS), dim3(BLOCK_THREADS), 0, stream>>>(
        inputs, target, eWih, eWhh, ebih, ebhh, dWih, dWhh, dbih, dbhh, oW, ob, out);
}